// Round 10
// baseline (422.412 us; speedup 1.0000x reference)
//
#include <hip/hip_runtime.h>
#include <hip/hip_bf16.h>
#include <math.h>

#define NH 16
#define DH 128
#define DM 2048
#define BB 2
#define TT 2048

typedef unsigned short u16;
typedef __attribute__((ext_vector_type(8))) __bf16 bf16x8;
typedef __attribute__((ext_vector_type(8))) u16 u16x8;
typedef __attribute__((ext_vector_type(4))) u16 u16x4;
typedef __attribute__((ext_vector_type(4))) float f32x4;

__device__ __forceinline__ float bf2f(u16 a){
  union { unsigned u; float f; } v; v.u = ((unsigned)a) << 16; return v.f;
}
__device__ __forceinline__ u16 f2bf(float f){
  union { float f; unsigned u; } v; v.f = f;
  unsigned r = v.u + 0x7fffu + ((v.u >> 16) & 1u);  // RNE
  return (u16)(r >> 16);
}
__device__ __forceinline__ __bf16 f2bfh(float f){
  u16 r = f2bf(f); __bf16 h; __builtin_memcpy(&h, &r, 2); return h;
}
__device__ __forceinline__ float bfh2f(__bf16 h){
  u16 r; __builtin_memcpy(&r, &h, 2); return bf2f(r);
}

// async global->LDS, 16B per lane. LDS dest = wave-uniform base + lane*16.
typedef const __attribute__((address_space(1))) unsigned int* gas_p;
typedef __attribute__((address_space(3))) unsigned int* las_p;
__device__ __forceinline__ void gl_lds16(const u16* g, u16* lds_uniform_base){
  __builtin_amdgcn_global_load_lds((gas_p)(const void*)g,
                                   (las_p)(void*)lds_uniform_base, 16, 0, 0);
}

#define SB() do{ asm volatile("" ::: "memory"); \
                 __builtin_amdgcn_s_barrier();  \
                 asm volatile("" ::: "memory"); }while(0)
#define WAITV8 asm volatile("s_waitcnt vmcnt(8)" ::: "memory")
#define WAITV0 asm volatile("s_waitcnt vmcnt(0)" ::: "memory")

// ---------------- prep4: 3 weight transposes (z<3) + x cvt (z==3) ----------
__global__ __launch_bounds__(256)
void prep4(const float* __restrict__ w0, const float* __restrict__ w1,
           const float* __restrict__ w2, const float* __restrict__ x,
           u16* __restrict__ dst, u16* __restrict__ xb){
  __shared__ u16 tile[32][33];
  const int z = blockIdx.z;
  const int tx = threadIdx.x, ty = threadIdx.y;
  if (z == 3){
    const int bid = blockIdx.y * 64 + blockIdx.x;
    const int tid = ty * 32 + tx;
    #pragma unroll
    for (int rep = 0; rep < 2; rep++){
      const int i = bid * 512 + rep * 256 + tid;
      const f32x4 v = *(const f32x4*)(x + (size_t)i * 4);
      u16x4 o;
      #pragma unroll
      for (int j = 0; j < 4; j++) o[j] = f2bf(v[j]);
      *(u16x4*)(xb + (size_t)i * 4) = o;
    }
    return;
  }
  const float* W = (z == 0) ? w0 : (z == 1) ? w1 : w2;
  u16* Wt = dst + (size_t)z * DM * DM;
  const int bx = blockIdx.x * 32, by = blockIdx.y * 32;
  #pragma unroll
  for (int i = 0; i < 32; i += 8)
    tile[ty + i][tx] = f2bf(W[(size_t)(by + ty + i) * DM + bx + tx]);
  __syncthreads();
  #pragma unroll
  for (int i = 0; i < 32; i += 8)
    Wt[(size_t)(bx + ty + i) * DM + by + tx] = tile[tx][ty + i];
}

// ---------------- W fp32 [K,N] -> Wt bf16 [N,K] (single, for wo) -----------
__global__ __launch_bounds__(256)
void transpose2048(const float* __restrict__ W, u16* __restrict__ Wt){
  __shared__ u16 tile[32][33];
  const int tx = threadIdx.x, ty = threadIdx.y;
  const int bx = blockIdx.x * 32, by = blockIdx.y * 32;
  #pragma unroll
  for (int i = 0; i < 32; i += 8)
    tile[ty + i][tx] = f2bf(W[(size_t)(by + ty + i) * DM + bx + tx]);
  __syncthreads();
  #pragma unroll
  for (int i = 0; i < 32; i += 8)
    Wt[(size_t)(bx + ty + i) * DM + by + tx] = tile[tx][ty + i];
}

// ---------------- fp32 -> bf16 elementwise (fallback path) ----------------
__global__ __launch_bounds__(256)
void cvt_f32_bf16(const float* __restrict__ src, u16* __restrict__ dst, int n4){
  const int i = blockIdx.x * 256 + threadIdx.x;
  if (i >= n4) return;
  const f32x4 v = *(const f32x4*)(src + (size_t)i * 4);
  u16x4 o;
  #pragma unroll
  for (int j = 0; j < 4; j++) o[j] = f2bf(v[j]);
  *(u16x4*)(dst + (size_t)i * 4) = o;
}

// ---------------- legacy 128x128 4-wave GEMM (fallback path) ---------------
__global__ __launch_bounds__(256)
void gemm_bt(const u16* __restrict__ A, const u16* __restrict__ Bt_base,
             void* __restrict__ C0, u16* __restrict__ Ck, u16* __restrict__ Cv,
             int mode0){
  __shared__ u16 As[2][128][32];
  __shared__ u16 Bs[2][128][32];
  const int z = blockIdx.z;
  const u16* Bt = Bt_base + (size_t)z * DM * DM;
  void* C = (z == 0) ? C0 : (z == 1) ? (void*)Ck : (void*)Cv;
  const int mode = (z == 0) ? mode0 : (z == 1) ? 3 : 2;

  const int tid = threadIdx.x;
  const int wave = tid >> 6, lane = tid & 63;
  const int wm = wave & 1, wn = wave >> 1;
  const int row16 = lane & 15, quad = lane >> 4;
  const int m0 = blockIdx.x * 128, n0 = blockIdx.y * 128;

  const f32x4 zero = {0.f, 0.f, 0.f, 0.f};
  f32x4 acc[4][4];
  #pragma unroll
  for (int i = 0; i < 4; i++)
    #pragma unroll
    for (int j = 0; j < 4; j++) acc[i][j] = zero;

  const int srow = lane >> 2;           // 0..15 within 16-row chunk
  const int scol = (lane & 3) * 8;      // u16 units, 16B per lane

  for (int k0 = 0; k0 < DM; k0 += 64){
    #pragma unroll
    for (int c = 0; c < 2; c++){
      const int rbase = wave * 32 + c * 16;
      const u16* pa = A  + (size_t)(m0 + rbase + srow) * DM + k0 + scol;
      const u16* pb = Bt + (size_t)(n0 + rbase + srow) * DM + k0 + scol;
      gl_lds16(pa,      &As[0][rbase][0]);
      gl_lds16(pa + 32, &As[1][rbase][0]);
      gl_lds16(pb,      &Bs[0][rbase][0]);
      gl_lds16(pb + 32, &Bs[1][rbase][0]);
    }
    __syncthreads();
    #pragma unroll
    for (int buf = 0; buf < 2; buf++){
      bf16x8 af[4], bfr[4];
      #pragma unroll
      for (int mt = 0; mt < 4; mt++)
        af[mt] = *(const bf16x8*)&As[buf][wm * 64 + mt * 16 + row16][quad * 8];
      #pragma unroll
      for (int nt = 0; nt < 4; nt++)
        bfr[nt] = *(const bf16x8*)&Bs[buf][wn * 64 + nt * 16 + row16][quad * 8];
      #pragma unroll
      for (int mt = 0; mt < 4; mt++)
        #pragma unroll
        for (int nt = 0; nt < 4; nt++)
          acc[mt][nt] = __builtin_amdgcn_mfma_f32_16x16x32_bf16(af[mt], bfr[nt], acc[mt][nt], 0, 0, 0);
    }
    __syncthreads();
  }

  #pragma unroll
  for (int mt = 0; mt < 4; mt++){
    #pragma unroll
    for (int nt = 0; nt < 4; nt++){
      #pragma unroll
      for (int r = 0; r < 4; r++){
        const int m = m0 + wm * 64 + mt * 16 + quad * 4 + r;
        const int n = n0 + wn * 64 + nt * 16 + row16;
        const int b = m >> 11, t = m & (TT - 1);
        const int hh = n >> 7, dh = n & (DH - 1);
        if (mode == 1){
          ((u16*)C)[(((size_t)(b * NH + hh) * TT + t) * DH) + dh] = f2bf(acc[mt][nt][r]);
        } else if (mode == 3){
          const int dhs = dh ^ ((t & 7) << 3);
          ((u16*)C)[(((size_t)(b * NH + hh) * TT + t) * DH) + dhs] = f2bf(acc[mt][nt][r]);
        } else if (mode == 2){
          const int ts = (t & 63) ^ ((dh & 7) << 3);
          ((u16*)C)[(((size_t)(b * NH + hh) * 32 + (t >> 6)) * 8192) + dh * 64 + ts] = f2bf(acc[mt][nt][r]);
        } else {
          ((float*)C)[(size_t)m * DM + n] = acc[mt][nt][r];
        }
      }
    }
  }
}

// ---------------- 128x256 8-wave GEMM (R10) --------------------------------
// R5-proven sync structure (stage-at-top -> compute -> __syncthreads, ONE
// barrier/tile, no raw-asm waits) at new geometry fixing the known losses:
// - grid: QKV 32x8x3 = 768 = 3 EXACT rounds at 1 block/CU (R1's 1.5-round
//   quantization tax removed); proj 32x8 = 256 = 1 exact round (vs 2).
// - 8 waves (2M x 4N), per-wave 64x64, acc 64 VGPR; 256 MFMA per barrier
//   (2x gemm_bt density).
// - chunk swizzle c' = c ^ (row&7) via pre-swizzled GLOBAL source (LDS dest
//   linear, R2/R5-proven conflicts->0): fragment reads uniform 8 lanes/slot.
//   gemm_bt pays 1.26e7 conflicts (~1.58x) on the LDS critical path.
// Buffer safety: STG(t+1 -> buf^1) overwrites data last read in tile t-1,
// whose reads precede t-1's end-__syncthreads. vmcnt drains at each
// __syncthreads with the whole tile-t compute (~1000cy) as cover.
__global__ __launch_bounds__(512)
void gemm8w(const u16* __restrict__ A, const u16* __restrict__ Bt_base,
            void* __restrict__ C0, u16* __restrict__ Ck, u16* __restrict__ Cv,
            int mode0){
  __shared__ u16 As[2][128][64];   // 32KB
  __shared__ u16 Bs[2][256][64];   // 64KB
  const int z = blockIdx.z;
  const u16* Bt = Bt_base + (size_t)z * DM * DM;
  void* C = (z == 0) ? C0 : (z == 1) ? (void*)Ck : (void*)Cv;
  const int mode = (z == 0) ? mode0 : (z == 1) ? 3 : 2;

  const int tid = threadIdx.x;
  const int wave = tid >> 6, lane = tid & 63;
  const int wm = wave >> 2, wn = wave & 3;     // 2M x 4N
  const int row16 = lane & 15, quad = lane >> 4;
  const int m0 = blockIdx.x * 128, n0 = blockIdx.y * 256;

  const f32x4 zero = {0.f, 0.f, 0.f, 0.f};
  f32x4 acc[4][4];
  #pragma unroll
  for (int i = 0; i < 4; i++)
    #pragma unroll
    for (int j = 0; j < 4; j++) acc[i][j] = zero;

  // staging: DMA unit = 8 rows x 128B; lane -> (row lane>>3, chunk lane&7);
  // source chunk pre-swizzled so physical chunk p holds logical p^(row&7).
  const int sr = lane >> 3;
  const int sc = ((lane & 7) ^ sr) * 8;        // u16 units
  const u16* aB = A  + (size_t)(m0 + wave * 16 + sr) * DM + sc;
  const u16* bB = Bt + (size_t)(n0 + wave * 32 + sr) * DM + sc;

  // 6 DMAs/thread per K-tile: A rows [w*16,+16) (2), B rows [w*32,+32) (4)
  #define STG8(bf, ku) do{ \
    gl_lds16(aB + (ku),                     &As[bf][wave * 16][0]); \
    gl_lds16(aB + (ku) + (size_t)8 * DM,    &As[bf][wave * 16 + 8][0]); \
    _Pragma("unroll") \
    for (int u = 0; u < 4; u++) \
      gl_lds16(bB + (ku) + (size_t)(u * 8) * DM, &Bs[bf][wave * 32 + u * 8][0]); \
  }while(0)

  STG8(0, 0);
  __syncthreads();

  for (int t = 0; t < 32; ++t){
    const int buf = t & 1;
    if (t < 31) STG8(buf ^ 1, (t + 1) * 64);   // covered by compute below
    #pragma unroll
    for (int kk = 0; kk < 2; kk++){
      const int pc = ((kk * 4 + quad) ^ (row16 & 7)) * 8;  // de-swizzle
      bf16x8 af[4], bk[4];
      #pragma unroll
      for (int mt = 0; mt < 4; mt++)
        af[mt] = *(const bf16x8*)&As[buf][wm * 64 + mt * 16 + row16][pc];
      #pragma unroll
      for (int nt = 0; nt < 4; nt++)
        bk[nt] = *(const bf16x8*)&Bs[buf][wn * 64 + nt * 16 + row16][pc];
      __builtin_amdgcn_s_setprio(1);
      #pragma unroll
      for (int mt = 0; mt < 4; mt++)
        #pragma unroll
        for (int nt = 0; nt < 4; nt++)
          acc[mt][nt] = __builtin_amdgcn_mfma_f32_16x16x32_bf16(af[mt], bk[nt], acc[mt][nt], 0, 0, 0);
      __builtin_amdgcn_s_setprio(0);
    }
    __syncthreads();   // drains t+1's DMAs (full-tile cover) + buf handoff
  }
  #undef STG8

  // epilogue: C/D layout row = quad*4+reg, col = lane&15
  #pragma unroll
  for (int mt = 0; mt < 4; mt++){
    #pragma unroll
    for (int nt = 0; nt < 4; nt++){
      #pragma unroll
      for (int r = 0; r < 4; r++){
        const int m = m0 + wm * 64 + mt * 16 + quad * 4 + r;
        const int n = n0 + wn * 64 + nt * 16 + row16;
        const int b = m >> 11, t = m & (TT - 1);
        const int hh = n >> 7, dh = n & (DH - 1);
        if (mode == 1){
          ((u16*)C)[(((size_t)(b * NH + hh) * TT + t) * DH) + dh] = f2bf(acc[mt][nt][r]);
        } else if (mode == 3){
          const int dhs = dh ^ ((t & 7) << 3);
          ((u16*)C)[(((size_t)(b * NH + hh) * TT + t) * DH) + dhs] = f2bf(acc[mt][nt][r]);
        } else if (mode == 2){
          const int ts = (t & 63) ^ ((dh & 7) << 3);
          ((u16*)C)[(((size_t)(b * NH + hh) * 32 + (t >> 6)) * 8192) + dh * 64 + ts] = f2bf(acc[mt][nt][r]);
        } else {
          ((float*)C)[(size_t)m * DM + n] = acc[mt][nt][r];
        }
      }
    }
  }
}

// ---------------- RoPE on K only, vectorized (u16x8, 8 pairs/thread) -------
__global__ __launch_bounds__(256)
void ropek(u16* __restrict__ kb, const int* __restrict__ posp){
  const int idx = blockIdx.x * 256 + threadIdx.x;   // one per (row, octet)
  const int sub = idx & 7;                           // 8 slots of 8 pairs
  const int row = idx >> 3;                          // b*H*T + h*T + t
  const int t = row & (TT - 1);
  int p0 = *posp; if (p0 < 0) p0 = 0;
  const float tf = (float)(p0 + t);
  const size_t base = (size_t)row * DH + sub * 8;
  u16x8 lo = *(const u16x8*)(kb + base);
  u16x8 hi = *(const u16x8*)(kb + base + 64);
  const int fx = (t & 7) << 3;
  #pragma unroll
  for (int j = 0; j < 8; j++){
    const int pl = (sub * 8 + j) ^ fx;
    const float inv = __expf(-(float)pl * (9.2103403719761836f / 64.f));
    const float a = tf * inv;
    const float sn = __sinf(a), cs = __cosf(a);
    const float k1 = bf2f(lo[j]), k2 = bf2f(hi[j]);
    lo[j] = f2bf(k1 * cs - k2 * sn);
    hi[j] = f2bf(k1 * sn + k2 * cs);
  }
  *(u16x8*)(kb + base)      = lo;
  *(u16x8*)(kb + base + 64) = hi;
}

// ---------------- causal flash attention v9 (R9-proven) --------------------
template<bool MASK>
__device__ __forceinline__ void attn_tile(
    int kt0, int qbase, int wave, int row16, int quad,
    const bf16x8 (&qf)[4],
    u16 (&k_s)[64][128], u16 (&vt_s)[128][64], u16 (&p_s)[4][16][68],
    f32x4 (&o_acc)[8], float (&l_acc)[4])
{
  const float scale = 0.08838834764831845f;  // 1/sqrt(128)
  const f32x4 zero = {0.f, 0.f, 0.f, 0.f};
  const int fx = (row16 & 7) << 3;           // XOR de-swizzle
  f32x4 s_acc[4];
  #pragma unroll
  for (int nt = 0; nt < 4; nt++) s_acc[nt] = zero;
  __builtin_amdgcn_s_setprio(1);
  #pragma unroll
  for (int st = 0; st < 4; st++)
    #pragma unroll
    for (int nt = 0; nt < 4; nt++){
      const bf16x8 kf = *(const bf16x8*)&k_s[nt * 16 + row16][(st * 32 + quad * 8) ^ fx];
      s_acc[nt] = __builtin_amdgcn_mfma_f32_16x16x32_bf16(qf[st], kf, s_acc[nt], 0, 0, 0);
    }
  __builtin_amdgcn_s_setprio(0);
  #pragma unroll
  for (int r = 0; r < 4; r++){
    float ps = 0.f;
    #pragma unroll
    for (int nt = 0; nt < 4; nt++){
      float p = __expf(s_acc[nt][r] * scale);
      if (MASK){
        const int qr = qbase + quad * 4 + r;
        if (kt0 + nt * 16 + row16 > qr) p = 0.f;
      }
      ps += p;
      p_s[wave][quad * 4 + r][nt * 16 + row16] = f2bf(p);
    }
    l_acc[r] += ps;
  }
  asm volatile("" ::: "memory");  // p_s wave-private; DS in-order per wave

  __builtin_amdgcn_s_setprio(1);
  #pragma unroll
  for (int kk = 0; kk < 2; kk++){
    const bf16x8 pf = *(const bf16x8*)&p_s[wave][row16][kk * 32 + quad * 8];
    #pragma unroll
    for (int nd = 0; nd < 8; nd++){
      const bf16x8 vb = *(const bf16x8*)&vt_s[nd * 16 + row16][(kk * 32 + quad * 8) ^ fx];
      o_acc[nd] = __builtin_amdgcn_mfma_f32_16x16x32_bf16(pf, vb, o_acc[nd], 0, 0, 0);
    }
  }
  __builtin_amdgcn_s_setprio(0);
}

__device__ __forceinline__ void qload_rope(
    const u16* __restrict__ q, size_t bho, int qbase, int p0,
    int row16, int quad, bf16x8 (&qf)[4])
{
  const u16* qp = q + bho + (size_t)(qbase + row16) * DH + quad * 8;
  #pragma unroll
  for (int st = 0; st < 4; st++) qf[st] = *(const bf16x8*)(qp + st * 32);
  const float tf = (float)(p0 + qbase + row16);
  #pragma unroll
  for (int st = 0; st < 2; st++){
    #pragma unroll
    for (int j = 0; j < 8; j++){
      const int dh = st * 32 + quad * 8 + j;
      const float inv = __expf(-(float)dh * (9.2103403719761836f / 64.f));
      const float a = tf * inv;
      const float sn = __sinf(a), cs = __cosf(a);
      const float lo = bfh2f(qf[st][j]), hi = bfh2f(qf[st + 2][j]);
      qf[st][j]     = f2bfh(lo * cs - hi * sn);
      qf[st + 2][j] = f2bfh(lo * sn + hi * cs);
    }
  }
}

__device__ __forceinline__ void owrite(
    u16* __restrict__ ctx, int bh, int qbase, int row16, int quad,
    f32x4 (&o_acc)[8], float (&l_acc)[4])
{
  #pragma unroll
  for (int r = 0; r < 4; r++){
    #pragma unroll
    for (int off = 1; off < 16; off <<= 1) l_acc[r] += __shfl_xor(l_acc[r], off, 64);
  }
  const int b = bh >> 4, h = bh & 15;
  #pragma unroll
  for (int nd = 0; nd < 8; nd++){
    #pragma unroll
    for (int r = 0; r < 4; r++){
      const int qr = qbase + quad * 4 + r;
      const size_t off = ((size_t)b * TT + qr) * DM + h * DH + nd * 16 + row16;
      ctx[off] = f2bf(o_acc[nd][r] / l_acc[r]);
    }
  }
}

__global__ __launch_bounds__(256)
void attn_fwd(const u16* __restrict__ q, const u16* __restrict__ k,
              const u16* __restrict__ vtg, u16* __restrict__ ctx,
              const int* __restrict__ posp){
  __shared__ u16 k_s[2][64][128];   // 32KB double-buffered [key][dh']
  __shared__ u16 vt_s[2][128][64];  // 32KB double-buffered [dh][t']
  __shared__ u16 p_s[4][16][68];    // 8.7KB per-wave P [q][key]
  const int tid = threadIdx.x;
  const int wave = tid >> 6, lane = tid & 63;
  const int row16 = lane & 15, quad = lane >> 4;
  const int i = blockIdx.x;         // 0..15
  const int bh = blockIdx.y;        // 0..31
  int p0 = *posp; if (p0 < 0) p0 = 0;
  const size_t bho = (size_t)bh * TT * DH;

  const int qbH = (31 - i) * 64 + wave * 16;   // heavy q-tile
  const int qbL = i * 64 + wave * 16;          // light q-tile (tiles subset)
  const int nT = 32 - i;                        // staged tiles t = 0..nT-1

  bf16x8 qfH[4], qfL[4];
  qload_rope(q, bho, qbH, p0, row16, quad, qfH);
  qload_rope(q, bho, qbL, p0, row16, quad, qfL);

  float lH[4] = {0.f, 0.f, 0.f, 0.f}, lL[4] = {0.f, 0.f, 0.f, 0.f};
  const f32x4 zero = {0.f, 0.f, 0.f, 0.f};
  f32x4 oH[8], oL[8];
  #pragma unroll
  for (int j = 0; j < 8; j++){ oH[j] = zero; oL[j] = zero; }

  // DMA lane maps: K 1KB = 4 rows x 256B; V 1KB = 8 rows x 128B
  const int kl_r = lane >> 4, kl_c = (lane & 15) * 8;
  const int vl_r = lane >> 3, vl_c = (lane & 7) * 8;

  #define ASTAGE(t, db) do{ \
    const int kt = (t) * 64; \
    _Pragma("unroll") \
    for (int u = 0; u < 4; u++){ \
      const int rb = wave * 16 + u * 4; \
      gl_lds16(k + bho + (size_t)(kt + rb + kl_r) * DH + kl_c, &k_s[db][rb][0]); \
    } \
    const u16* vpan = vtg + ((size_t)bh * 32 + (t)) * 8192; \
    _Pragma("unroll") \
    for (int u = 0; u < 4; u++){ \
      const int rb = wave * 32 + u * 8; \
      gl_lds16(vpan + (size_t)(rb + vl_r) * 64 + vl_c, &vt_s[db][rb][0]); \
    } \
  }while(0)

  ASTAGE(0, 0);
  for (int t = 0; t < nT; ++t){
    const int db = t & 1;
    if (t + 1 < nT){
      ASTAGE(t + 1, db ^ 1);   // issue-early: covered by compute(t)
      WAITV8;                  // tile t landed; t+1 stays in flight
    } else {
      WAITV0;                  // last tile: drain
    }
    SB();                      // all waves' tile-t DMAs visible
    // heavy q: every tile; diagonal (mask) at t == nT-1
    if (t < nT - 1)
      attn_tile<false>(t * 64, qbH, wave, row16, quad, qfH, k_s[db], vt_s[db], p_s, oH, lH);
    else
      attn_tile<true >(t * 64, qbH, wave, row16, quad, qfH, k_s[db], vt_s[db], p_s, oH, lH);
    // light q: tiles t <= i only; diagonal at t == i
    if (t < i)
      attn_tile<false>(t * 64, qbL, wave, row16, quad, qfL, k_s[db], vt_s[db], p_s, oL, lL);
    else if (t == i)
      attn_tile<true >(t * 64, qbL, wave, row16, quad, qfL, k_s[db], vt_s[db], p_s, oL, lL);
    SB();                      // buf t free for restage (reads consumed)
  }
  #undef ASTAGE

  owrite(ctx, bh, qbH, row16, quad, oH, lH);
  owrite(ctx, bh, qbL, row16, quad, oL, lL);
}

extern "C" void kernel_launch(void* const* d_in, const int* in_sizes, int n_in,
                              void* d_out, int out_size, void* d_ws, size_t ws_size,
                              hipStream_t stream){
  const float* x  = (const float*)d_in[0];   // fp32 per reference
  const float* wq = (const float*)d_in[1];
  const float* wk = (const float*)d_in[2];
  const float* wv = (const float*)d_in[3];
  const float* wo = (const float*)d_in[4];
  const int* pos  = (const int*)d_in[5];

  char* ws = (char*)d_ws;
  const dim3 tg(64, 64), tb(32, 8);

  if (ws_size >= 92274688ull){
    // fused path: xb 16MB | wt3 25.2MB | qb 16 | kb 16 | vtg 16 = 92.3MB
    u16* xb  = (u16*)ws;                  u16* cb = xb;
    u16* wt3 = (u16*)(ws + 16777216);
    u16* qb  = (u16*)(ws + 41943040);
    u16* kb  = (u16*)(ws + 58720256);
    u16* vtg = (u16*)(ws + 75497472);

    prep4<<<dim3(64, 64, 4), tb, 0, stream>>>(wq, wk, wv, x, wt3, xb);
    gemm8w<<<dim3(32, 8, 3), 512, 0, stream>>>(xb, wt3, qb, kb, vtg, 1);
    transpose2048<<<tg, tb, 0, stream>>>(wo, wt3);   // slot0 (wq^T) dead; hoisted
    ropek<<<2048, 256, 0, stream>>>(kb, pos);
    attn_fwd<<<dim3(16, 32), 256, 0, stream>>>(qb, kb, vtg, cb, pos);
    gemm8w<<<dim3(32, 8, 1), 512, 0, stream>>>(cb, wt3, d_out, 0, 0, 0);
  } else {
    // fallback (75.5MB): xb/cb 16 | wt 8 | qb 16 | kb 16 | vtg 16
    u16* xb  = (u16*)ws;                  u16* cb = xb;
    u16* wt  = (u16*)(ws + 16777216);
    u16* qb  = (u16*)(ws + 25165824);
    u16* kb  = (u16*)(ws + 41943040);
    u16* vtg = (u16*)(ws + 58720256);

    cvt_f32_bf16<<<8192, 256, 0, stream>>>(x, xb, 2097152);
    transpose2048<<<tg, tb, 0, stream>>>(wq, wt);
    gemm_bt<<<dim3(32, 16, 1), 256, 0, stream>>>(xb, wt, qb, 0, 0, 1);
    transpose2048<<<tg, tb, 0, stream>>>(wk, wt);
    gemm_bt<<<dim3(32, 16, 1), 256, 0, stream>>>(xb, wt, kb, 0, 0, 3);
    transpose2048<<<tg, tb, 0, stream>>>(wv, wt);
    gemm_bt<<<dim3(32, 16, 1), 256, 0, stream>>>(xb, wt, vtg, 0, 0, 2);
    ropek<<<2048, 256, 0, stream>>>(kb, pos);
    attn_fwd<<<dim3(16, 32), 256, 0, stream>>>(qb, kb, vtg, cb, pos);
    transpose2048<<<tg, tb, 0, stream>>>(wo, wt);
    gemm_bt<<<dim3(32, 16, 1), 256, 0, stream>>>(cb, wt, d_out, 0, 0, 0);
  }
}

// Round 11
// 420.759 us; speedup vs baseline: 1.0039x; 1.0039x over previous
//
#include <hip/hip_runtime.h>
#include <hip/hip_bf16.h>
#include <math.h>

#define NH 16
#define DH 128
#define DM 2048
#define BB 2
#define TT 2048

typedef unsigned short u16;
typedef __attribute__((ext_vector_type(8))) __bf16 bf16x8;
typedef __attribute__((ext_vector_type(8))) u16 u16x8;
typedef __attribute__((ext_vector_type(4))) u16 u16x4;
typedef __attribute__((ext_vector_type(4))) float f32x4;

__device__ __forceinline__ float bf2f(u16 a){
  union { unsigned u; float f; } v; v.u = ((unsigned)a) << 16; return v.f;
}
__device__ __forceinline__ u16 f2bf(float f){
  union { float f; unsigned u; } v; v.f = f;
  unsigned r = v.u + 0x7fffu + ((v.u >> 16) & 1u);  // RNE
  return (u16)(r >> 16);
}
__device__ __forceinline__ __bf16 f2bfh(float f){
  u16 r = f2bf(f); __bf16 h; __builtin_memcpy(&h, &r, 2); return h;
}
__device__ __forceinline__ float bfh2f(__bf16 h){
  u16 r; __builtin_memcpy(&r, &h, 2); return bf2f(r);
}

// async global->LDS, 16B per lane. LDS dest = wave-uniform base + lane*16.
typedef const __attribute__((address_space(1))) unsigned int* gas_p;
typedef __attribute__((address_space(3))) unsigned int* las_p;
__device__ __forceinline__ void gl_lds16(const u16* g, u16* lds_uniform_base){
  __builtin_amdgcn_global_load_lds((gas_p)(const void*)g,
                                   (las_p)(void*)lds_uniform_base, 16, 0, 0);
}

#define SB() do{ asm volatile("" ::: "memory"); \
                 __builtin_amdgcn_s_barrier();  \
                 asm volatile("" ::: "memory"); }while(0)
#define WAITV8 asm volatile("s_waitcnt vmcnt(8)" ::: "memory")
#define WAITV6 asm volatile("s_waitcnt vmcnt(6)" ::: "memory")
#define WAITV0 asm volatile("s_waitcnt vmcnt(0)" ::: "memory")

// ---------------- prep4: 3 weight transposes (z<3) + x cvt (z==3) ----------
__global__ __launch_bounds__(256)
void prep4(const float* __restrict__ w0, const float* __restrict__ w1,
           const float* __restrict__ w2, const float* __restrict__ x,
           u16* __restrict__ dst, u16* __restrict__ xb){
  __shared__ u16 tile[32][33];
  const int z = blockIdx.z;
  const int tx = threadIdx.x, ty = threadIdx.y;
  if (z == 3){
    const int bid = blockIdx.y * 64 + blockIdx.x;
    const int tid = ty * 32 + tx;
    #pragma unroll
    for (int rep = 0; rep < 2; rep++){
      const int i = bid * 512 + rep * 256 + tid;
      const f32x4 v = *(const f32x4*)(x + (size_t)i * 4);
      u16x4 o;
      #pragma unroll
      for (int j = 0; j < 4; j++) o[j] = f2bf(v[j]);
      *(u16x4*)(xb + (size_t)i * 4) = o;
    }
    return;
  }
  const float* W = (z == 0) ? w0 : (z == 1) ? w1 : w2;
  u16* Wt = dst + (size_t)z * DM * DM;
  const int bx = blockIdx.x * 32, by = blockIdx.y * 32;
  #pragma unroll
  for (int i = 0; i < 32; i += 8)
    tile[ty + i][tx] = f2bf(W[(size_t)(by + ty + i) * DM + bx + tx]);
  __syncthreads();
  #pragma unroll
  for (int i = 0; i < 32; i += 8)
    Wt[(size_t)(bx + ty + i) * DM + by + tx] = tile[tx][ty + i];
}

// ---------------- W fp32 [K,N] -> Wt bf16 [N,K] (single, for wo) -----------
__global__ __launch_bounds__(256)
void transpose2048(const float* __restrict__ W, u16* __restrict__ Wt){
  __shared__ u16 tile[32][33];
  const int tx = threadIdx.x, ty = threadIdx.y;
  const int bx = blockIdx.x * 32, by = blockIdx.y * 32;
  #pragma unroll
  for (int i = 0; i < 32; i += 8)
    tile[ty + i][tx] = f2bf(W[(size_t)(by + ty + i) * DM + bx + tx]);
  __syncthreads();
  #pragma unroll
  for (int i = 0; i < 32; i += 8)
    Wt[(size_t)(bx + ty + i) * DM + by + tx] = tile[tx][ty + i];
}

// ---------------- fp32 -> bf16 elementwise (fallback path) ----------------
__global__ __launch_bounds__(256)
void cvt_f32_bf16(const float* __restrict__ src, u16* __restrict__ dst, int n4){
  const int i = blockIdx.x * 256 + threadIdx.x;
  if (i >= n4) return;
  const f32x4 v = *(const f32x4*)(src + (size_t)i * 4);
  u16x4 o;
  #pragma unroll
  for (int j = 0; j < 4; j++) o[j] = f2bf(v[j]);
  *(u16x4*)(dst + (size_t)i * 4) = o;
}

// ---------------- 128x128 4-wave GEMM (m97 structure; proj + fallback) -----
__global__ __launch_bounds__(256)
void gemm_bt(const u16* __restrict__ A, const u16* __restrict__ Bt_base,
             void* __restrict__ C0, u16* __restrict__ Ck, u16* __restrict__ Cv,
             int mode0){
  __shared__ u16 As[2][128][32];
  __shared__ u16 Bs[2][128][32];
  const int z = blockIdx.z;
  const u16* Bt = Bt_base + (size_t)z * DM * DM;
  void* C = (z == 0) ? C0 : (z == 1) ? (void*)Ck : (void*)Cv;
  const int mode = (z == 0) ? mode0 : (z == 1) ? 3 : 2;

  const int tid = threadIdx.x;
  const int wave = tid >> 6, lane = tid & 63;
  const int wm = wave & 1, wn = wave >> 1;
  const int row16 = lane & 15, quad = lane >> 4;
  const int m0 = blockIdx.x * 128, n0 = blockIdx.y * 128;

  const f32x4 zero = {0.f, 0.f, 0.f, 0.f};
  f32x4 acc[4][4];
  #pragma unroll
  for (int i = 0; i < 4; i++)
    #pragma unroll
    for (int j = 0; j < 4; j++) acc[i][j] = zero;

  const int srow = lane >> 2;           // 0..15 within 16-row chunk
  const int scol = (lane & 3) * 8;      // u16 units, 16B per lane

  for (int k0 = 0; k0 < DM; k0 += 64){
    #pragma unroll
    for (int c = 0; c < 2; c++){
      const int rbase = wave * 32 + c * 16;
      const u16* pa = A  + (size_t)(m0 + rbase + srow) * DM + k0 + scol;
      const u16* pb = Bt + (size_t)(n0 + rbase + srow) * DM + k0 + scol;
      gl_lds16(pa,      &As[0][rbase][0]);
      gl_lds16(pa + 32, &As[1][rbase][0]);
      gl_lds16(pb,      &Bs[0][rbase][0]);
      gl_lds16(pb + 32, &Bs[1][rbase][0]);
    }
    __syncthreads();
    #pragma unroll
    for (int buf = 0; buf < 2; buf++){
      bf16x8 af[4], bfr[4];
      #pragma unroll
      for (int mt = 0; mt < 4; mt++)
        af[mt] = *(const bf16x8*)&As[buf][wm * 64 + mt * 16 + row16][quad * 8];
      #pragma unroll
      for (int nt = 0; nt < 4; nt++)
        bfr[nt] = *(const bf16x8*)&Bs[buf][wn * 64 + nt * 16 + row16][quad * 8];
      #pragma unroll
      for (int mt = 0; mt < 4; mt++)
        #pragma unroll
        for (int nt = 0; nt < 4; nt++)
          acc[mt][nt] = __builtin_amdgcn_mfma_f32_16x16x32_bf16(af[mt], bfr[nt], acc[mt][nt], 0, 0, 0);
    }
    __syncthreads();
  }

  #pragma unroll
  for (int mt = 0; mt < 4; mt++){
    #pragma unroll
    for (int nt = 0; nt < 4; nt++){
      #pragma unroll
      for (int r = 0; r < 4; r++){
        const int m = m0 + wm * 64 + mt * 16 + quad * 4 + r;
        const int n = n0 + wn * 64 + nt * 16 + row16;
        const int b = m >> 11, t = m & (TT - 1);
        const int hh = n >> 7, dh = n & (DH - 1);
        if (mode == 1){
          ((u16*)C)[(((size_t)(b * NH + hh) * TT + t) * DH) + dh] = f2bf(acc[mt][nt][r]);
        } else if (mode == 3){
          const int dhs = dh ^ ((t & 7) << 3);
          ((u16*)C)[(((size_t)(b * NH + hh) * TT + t) * DH) + dhs] = f2bf(acc[mt][nt][r]);
        } else if (mode == 2){
          const int ts = (t & 63) ^ ((dh & 7) << 3);
          ((u16*)C)[(((size_t)(b * NH + hh) * 32 + (t >> 6)) * 8192) + dh * 64 + ts] = f2bf(acc[mt][nt][r]);
        } else {
          ((float*)C)[(size_t)m * DM + n] = acc[mt][nt][r];
        }
      }
    }
  }
}

// ---------------- 128x256 8-wave GEMM v2 (R11): v7-pattern counted vmcnt ---
// R10 diagnosis: gemm8w (1 block/CU) lost to gemm_bt because __syncthreads'
// vmcnt(0) drain has NO inter-block cover at 1 block/CU — same disease attn
// had pre-v7 (measured R6: occupancy ~1 block/CU, MfmaUtil 10.6%; v7 pattern
// cured it 129.8 -> ~79us). Transplant the exact v7-proven sync:
//   iter t: STG8(t+1 -> buf^1); vmcnt(6) [t's 6 loads retired, t+1's in
//           flight]; s_barrier; 64-MFMA single compute region; s_barrier
// vmcnt never drains to 0 until the peeled last tile. Race-freedom as v7:
// buf^1 was freed by iter t-1's closing barrier; per-wave counted wait +
// barrier joins all waves' loads. Geometry/swizzle/grid unchanged from R10
// (conflicts 0, 768 blocks = 3 exact rounds, setprio, 2x MFMA density).
__global__ __launch_bounds__(512)
void gemm8w2(const u16* __restrict__ A, const u16* __restrict__ Bt_base,
             void* __restrict__ C0, u16* __restrict__ Ck, u16* __restrict__ Cv,
             int mode0){
  __shared__ u16 As[2][128][64];   // 32KB
  __shared__ u16 Bs[2][256][64];   // 64KB
  const int z = blockIdx.z;
  const u16* Bt = Bt_base + (size_t)z * DM * DM;
  void* C = (z == 0) ? C0 : (z == 1) ? (void*)Ck : (void*)Cv;
  const int mode = (z == 0) ? mode0 : (z == 1) ? 3 : 2;

  const int tid = threadIdx.x;
  const int wave = tid >> 6, lane = tid & 63;
  const int wm = wave >> 2, wn = wave & 3;     // 2M x 4N
  const int row16 = lane & 15, quad = lane >> 4;
  const int m0 = blockIdx.x * 128, n0 = blockIdx.y * 256;

  const f32x4 zero = {0.f, 0.f, 0.f, 0.f};
  f32x4 acc[4][4];
  #pragma unroll
  for (int i = 0; i < 4; i++)
    #pragma unroll
    for (int j = 0; j < 4; j++) acc[i][j] = zero;

  // staging: DMA unit = 8 rows x 128B; lane -> (row lane>>3, chunk lane&7);
  // source chunk pre-swizzled so physical chunk p holds logical p^(row&7).
  const int sr = lane >> 3;
  const int sc = ((lane & 7) ^ sr) * 8;        // u16 units
  const u16* aB = A  + (size_t)(m0 + wave * 16 + sr) * DM + sc;
  const u16* bB = Bt + (size_t)(n0 + wave * 32 + sr) * DM + sc;

  // 6 DMAs/thread per K-tile: A rows [w*16,+16) (2), B rows [w*32,+32) (4)
  #define STG8(bf, ku) do{ \
    gl_lds16(aB + (ku),                     &As[bf][wave * 16][0]); \
    gl_lds16(aB + (ku) + (size_t)8 * DM,    &As[bf][wave * 16 + 8][0]); \
    _Pragma("unroll") \
    for (int u = 0; u < 4; u++) \
      gl_lds16(bB + (ku) + (size_t)(u * 8) * DM, &Bs[bf][wave * 32 + u * 8][0]); \
  }while(0)

  STG8(0, 0);                       // tile 0 in flight (6 loads)

  for (int t = 0; t < 32; ++t){
    const int buf = t & 1;
    if (t < 31){
      STG8(buf ^ 1, (t + 1) * 64);  // buf^1 freed by iter t-1's closing SB
      WAITV6;                       // tile t landed; t+1 stays in flight
    } else {
      WAITV0;                       // last tile: drain
    }
    SB();                           // all waves' tile-t DMAs visible
    #pragma unroll
    for (int kk = 0; kk < 2; kk++){
      const int pc = ((kk * 4 + quad) ^ (row16 & 7)) * 8;  // de-swizzle
      bf16x8 af[4], bk[4];
      #pragma unroll
      for (int mt = 0; mt < 4; mt++)
        af[mt] = *(const bf16x8*)&As[buf][wm * 64 + mt * 16 + row16][pc];
      #pragma unroll
      for (int nt = 0; nt < 4; nt++)
        bk[nt] = *(const bf16x8*)&Bs[buf][wn * 64 + nt * 16 + row16][pc];
      __builtin_amdgcn_s_setprio(1);
      #pragma unroll
      for (int mt = 0; mt < 4; mt++)
        #pragma unroll
        for (int nt = 0; nt < 4; nt++)
          acc[mt][nt] = __builtin_amdgcn_mfma_f32_16x16x32_bf16(af[mt], bk[nt], acc[mt][nt], 0, 0, 0);
      __builtin_amdgcn_s_setprio(0);
    }
    SB();                           // buf free for restage next iter
  }
  #undef STG8

  // epilogue: C/D layout row = quad*4+reg, col = lane&15
  #pragma unroll
  for (int mt = 0; mt < 4; mt++){
    #pragma unroll
    for (int nt = 0; nt < 4; nt++){
      #pragma unroll
      for (int r = 0; r < 4; r++){
        const int m = m0 + wm * 64 + mt * 16 + quad * 4 + r;
        const int n = n0 + wn * 64 + nt * 16 + row16;
        const int b = m >> 11, t = m & (TT - 1);
        const int hh = n >> 7, dh = n & (DH - 1);
        if (mode == 1){
          ((u16*)C)[(((size_t)(b * NH + hh) * TT + t) * DH) + dh] = f2bf(acc[mt][nt][r]);
        } else if (mode == 3){
          const int dhs = dh ^ ((t & 7) << 3);
          ((u16*)C)[(((size_t)(b * NH + hh) * TT + t) * DH) + dhs] = f2bf(acc[mt][nt][r]);
        } else if (mode == 2){
          const int ts = (t & 63) ^ ((dh & 7) << 3);
          ((u16*)C)[(((size_t)(b * NH + hh) * 32 + (t >> 6)) * 8192) + dh * 64 + ts] = f2bf(acc[mt][nt][r]);
        } else {
          ((float*)C)[(size_t)m * DM + n] = acc[mt][nt][r];
        }
      }
    }
  }
}

// ---------------- RoPE on K only, vectorized (u16x8, 8 pairs/thread) -------
__global__ __launch_bounds__(256)
void ropek(u16* __restrict__ kb, const int* __restrict__ posp){
  const int idx = blockIdx.x * 256 + threadIdx.x;   // one per (row, octet)
  const int sub = idx & 7;                           // 8 slots of 8 pairs
  const int row = idx >> 3;                          // b*H*T + h*T + t
  const int t = row & (TT - 1);
  int p0 = *posp; if (p0 < 0) p0 = 0;
  const float tf = (float)(p0 + t);
  const size_t base = (size_t)row * DH + sub * 8;
  u16x8 lo = *(const u16x8*)(kb + base);
  u16x8 hi = *(const u16x8*)(kb + base + 64);
  const int fx = (t & 7) << 3;
  #pragma unroll
  for (int j = 0; j < 8; j++){
    const int pl = (sub * 8 + j) ^ fx;
    const float inv = __expf(-(float)pl * (9.2103403719761836f / 64.f));
    const float a = tf * inv;
    const float sn = __sinf(a), cs = __cosf(a);
    const float k1 = bf2f(lo[j]), k2 = bf2f(hi[j]);
    lo[j] = f2bf(k1 * cs - k2 * sn);
    hi[j] = f2bf(k1 * sn + k2 * cs);
  }
  *(u16x8*)(kb + base)      = lo;
  *(u16x8*)(kb + base + 64) = hi;
}

// ---------------- causal flash attention v9 (R9-proven) --------------------
template<bool MASK>
__device__ __forceinline__ void attn_tile(
    int kt0, int qbase, int wave, int row16, int quad,
    const bf16x8 (&qf)[4],
    u16 (&k_s)[64][128], u16 (&vt_s)[128][64], u16 (&p_s)[4][16][68],
    f32x4 (&o_acc)[8], float (&l_acc)[4])
{
  const float scale = 0.08838834764831845f;  // 1/sqrt(128)
  const f32x4 zero = {0.f, 0.f, 0.f, 0.f};
  const int fx = (row16 & 7) << 3;           // XOR de-swizzle
  f32x4 s_acc[4];
  #pragma unroll
  for (int nt = 0; nt < 4; nt++) s_acc[nt] = zero;
  __builtin_amdgcn_s_setprio(1);
  #pragma unroll
  for (int st = 0; st < 4; st++)
    #pragma unroll
    for (int nt = 0; nt < 4; nt++){
      const bf16x8 kf = *(const bf16x8*)&k_s[nt * 16 + row16][(st * 32 + quad * 8) ^ fx];
      s_acc[nt] = __builtin_amdgcn_mfma_f32_16x16x32_bf16(qf[st], kf, s_acc[nt], 0, 0, 0);
    }
  __builtin_amdgcn_s_setprio(0);
  #pragma unroll
  for (int r = 0; r < 4; r++){
    float ps = 0.f;
    #pragma unroll
    for (int nt = 0; nt < 4; nt++){
      float p = __expf(s_acc[nt][r] * scale);
      if (MASK){
        const int qr = qbase + quad * 4 + r;
        if (kt0 + nt * 16 + row16 > qr) p = 0.f;
      }
      ps += p;
      p_s[wave][quad * 4 + r][nt * 16 + row16] = f2bf(p);
    }
    l_acc[r] += ps;
  }
  asm volatile("" ::: "memory");  // p_s wave-private; DS in-order per wave

  __builtin_amdgcn_s_setprio(1);
  #pragma unroll
  for (int kk = 0; kk < 2; kk++){
    const bf16x8 pf = *(const bf16x8*)&p_s[wave][row16][kk * 32 + quad * 8];
    #pragma unroll
    for (int nd = 0; nd < 8; nd++){
      const bf16x8 vb = *(const bf16x8*)&vt_s[nd * 16 + row16][(kk * 32 + quad * 8) ^ fx];
      o_acc[nd] = __builtin_amdgcn_mfma_f32_16x16x32_bf16(pf, vb, o_acc[nd], 0, 0, 0);
    }
  }
  __builtin_amdgcn_s_setprio(0);
}

__device__ __forceinline__ void owrite(
    u16* __restrict__ ctx, int bh, int qbase, int row16, int quad,
    f32x4 (&o_acc)[8], float (&l_acc)[4])
{
  #pragma unroll
  for (int r = 0; r < 4; r++){
    #pragma unroll
    for (int off = 1; off < 16; off <<= 1) l_acc[r] += __shfl_xor(l_acc[r], off, 64);
  }
  const int b = bh >> 4, h = bh & 15;
  #pragma unroll
  for (int nd = 0; nd < 8; nd++){
    #pragma unroll
    for (int r = 0; r < 4; r++){
      const int qr = qbase + quad * 4 + r;
      const size_t off = ((size_t)b * TT + qr) * DM + h * DH + nd * 16 + row16;
      ctx[off] = f2bf(o_acc[nd][r] / l_acc[r]);
    }
  }
}

__global__ __launch_bounds__(256)
void attn_fwd(const u16* __restrict__ q, const u16* __restrict__ k,
              const u16* __restrict__ vtg, u16* __restrict__ ctx,
              const int* __restrict__ posp){
  __shared__ u16 k_s[2][64][128];   // 32KB double-buffered [key][dh']
  __shared__ u16 vt_s[2][128][64];  // 32KB double-buffered [dh][t']
  __shared__ u16 p_s[4][16][68];    // 8.7KB per-wave P [q][key]
  const int tid = threadIdx.x;
  const int wave = tid >> 6, lane = tid & 63;
  const int row16 = lane & 15, quad = lane >> 4;
  const int i = blockIdx.x;         // 0..15
  const int bh = blockIdx.y;        // 0..31
  int p0 = *posp; if (p0 < 0) p0 = 0;
  const size_t bho = (size_t)bh * TT * DH;

  const int qbH = (31 - i) * 64 + wave * 16;   // heavy q-tile
  const int qbL = i * 64 + wave * 16;          // light q-tile (tiles subset)
  const int nT = 32 - i;                        // staged tiles t = 0..nT-1

  // fused Q-RoPE for both q-tiles, sharing the 16 inv-freq exps (R11)
  bf16x8 qfH[4], qfL[4];
  {
    const u16* qpH = q + bho + (size_t)(qbH + row16) * DH + quad * 8;
    const u16* qpL = q + bho + (size_t)(qbL + row16) * DH + quad * 8;
    #pragma unroll
    for (int st = 0; st < 4; st++){
      qfH[st] = *(const bf16x8*)(qpH + st * 32);
      qfL[st] = *(const bf16x8*)(qpL + st * 32);
    }
    const float tfH = (float)(p0 + qbH + row16);
    const float tfL = (float)(p0 + qbL + row16);
    #pragma unroll
    for (int st = 0; st < 2; st++){
      #pragma unroll
      for (int j = 0; j < 8; j++){
        const int dh = st * 32 + quad * 8 + j;
        const float inv = __expf(-(float)dh * (9.2103403719761836f / 64.f));
        float a = tfH * inv;
        float sn = __sinf(a), cs = __cosf(a);
        float lo = bfh2f(qfH[st][j]), hi = bfh2f(qfH[st + 2][j]);
        qfH[st][j]     = f2bfh(lo * cs - hi * sn);
        qfH[st + 2][j] = f2bfh(lo * sn + hi * cs);
        a = tfL * inv;
        sn = __sinf(a); cs = __cosf(a);
        lo = bfh2f(qfL[st][j]); hi = bfh2f(qfL[st + 2][j]);
        qfL[st][j]     = f2bfh(lo * cs - hi * sn);
        qfL[st + 2][j] = f2bfh(lo * sn + hi * cs);
      }
    }
  }

  float lH[4] = {0.f, 0.f, 0.f, 0.f}, lL[4] = {0.f, 0.f, 0.f, 0.f};
  const f32x4 zero = {0.f, 0.f, 0.f, 0.f};
  f32x4 oH[8], oL[8];
  #pragma unroll
  for (int j = 0; j < 8; j++){ oH[j] = zero; oL[j] = zero; }

  // DMA lane maps: K 1KB = 4 rows x 256B; V 1KB = 8 rows x 128B
  const int kl_r = lane >> 4, kl_c = (lane & 15) * 8;
  const int vl_r = lane >> 3, vl_c = (lane & 7) * 8;

  #define ASTAGE(t, db) do{ \
    const int kt = (t) * 64; \
    _Pragma("unroll") \
    for (int u = 0; u < 4; u++){ \
      const int rb = wave * 16 + u * 4; \
      gl_lds16(k + bho + (size_t)(kt + rb + kl_r) * DH + kl_c, &k_s[db][rb][0]); \
    } \
    const u16* vpan = vtg + ((size_t)bh * 32 + (t)) * 8192; \
    _Pragma("unroll") \
    for (int u = 0; u < 4; u++){ \
      const int rb = wave * 32 + u * 8; \
      gl_lds16(vpan + (size_t)(rb + vl_r) * 64 + vl_c, &vt_s[db][rb][0]); \
    } \
  }while(0)

  ASTAGE(0, 0);
  for (int t = 0; t < nT; ++t){
    const int db = t & 1;
    if (t + 1 < nT){
      ASTAGE(t + 1, db ^ 1);   // issue-early: covered by compute(t)
      WAITV8;                  // tile t landed; t+1 stays in flight
    } else {
      WAITV0;                  // last tile: drain
    }
    SB();                      // all waves' tile-t DMAs visible
    // heavy q: every tile; diagonal (mask) at t == nT-1
    if (t < nT - 1)
      attn_tile<false>(t * 64, qbH, wave, row16, quad, qfH, k_s[db], vt_s[db], p_s, oH, lH);
    else
      attn_tile<true >(t * 64, qbH, wave, row16, quad, qfH, k_s[db], vt_s[db], p_s, oH, lH);
    // light q: tiles t <= i only; diagonal at t == i
    if (t < i)
      attn_tile<false>(t * 64, qbL, wave, row16, quad, qfL, k_s[db], vt_s[db], p_s, oL, lL);
    else if (t == i)
      attn_tile<true >(t * 64, qbL, wave, row16, quad, qfL, k_s[db], vt_s[db], p_s, oL, lL);
    SB();                      // buf t free for restage (reads consumed)
  }
  #undef ASTAGE

  owrite(ctx, bh, qbH, row16, quad, oH, lH);
  owrite(ctx, bh, qbL, row16, quad, oL, lL);
}

extern "C" void kernel_launch(void* const* d_in, const int* in_sizes, int n_in,
                              void* d_out, int out_size, void* d_ws, size_t ws_size,
                              hipStream_t stream){
  const float* x  = (const float*)d_in[0];   // fp32 per reference
  const float* wq = (const float*)d_in[1];
  const float* wk = (const float*)d_in[2];
  const float* wv = (const float*)d_in[3];
  const float* wo = (const float*)d_in[4];
  const int* pos  = (const int*)d_in[5];

  char* ws = (char*)d_ws;
  const dim3 tg(64, 64), tb(32, 8);

  if (ws_size >= 92274688ull){
    // fused path: xb 16MB | wt3 25.2MB | qb 16 | kb 16 | vtg 16 = 92.3MB
    u16* xb  = (u16*)ws;                  u16* cb = xb;
    u16* wt3 = (u16*)(ws + 16777216);
    u16* qb  = (u16*)(ws + 41943040);
    u16* kb  = (u16*)(ws + 58720256);
    u16* vtg = (u16*)(ws + 75497472);

    prep4<<<dim3(64, 64, 4), tb, 0, stream>>>(wq, wk, wv, x, wt3, xb);
    gemm8w2<<<dim3(32, 8, 3), 512, 0, stream>>>(xb, wt3, qb, kb, vtg, 1);
    transpose2048<<<tg, tb, 0, stream>>>(wo, wt3);   // slot0 (wq^T) dead; hoisted
    ropek<<<2048, 256, 0, stream>>>(kb, pos);
    attn_fwd<<<dim3(16, 32), 256, 0, stream>>>(qb, kb, vtg, cb, pos);
    gemm_bt<<<dim3(32, 16, 1), 256, 0, stream>>>(cb, wt3, d_out, 0, 0, 0);
  } else {
    // fallback (75.5MB): xb/cb 16 | wt 8 | qb 16 | kb 16 | vtg 16
    u16* xb  = (u16*)ws;                  u16* cb = xb;
    u16* wt  = (u16*)(ws + 16777216);
    u16* qb  = (u16*)(ws + 25165824);
    u16* kb  = (u16*)(ws + 41943040);
    u16* vtg = (u16*)(ws + 58720256);

    cvt_f32_bf16<<<8192, 256, 0, stream>>>(x, xb, 2097152);
    transpose2048<<<tg, tb, 0, stream>>>(wq, wt);
    gemm_bt<<<dim3(32, 16, 1), 256, 0, stream>>>(xb, wt, qb, 0, 0, 1);
    transpose2048<<<tg, tb, 0, stream>>>(wk, wt);
    gemm_bt<<<dim3(32, 16, 1), 256, 0, stream>>>(xb, wt, kb, 0, 0, 3);
    transpose2048<<<tg, tb, 0, stream>>>(wv, wt);
    gemm_bt<<<dim3(32, 16, 1), 256, 0, stream>>>(xb, wt, vtg, 0, 0, 2);
    ropek<<<2048, 256, 0, stream>>>(kb, pos);
    attn_fwd<<<dim3(16, 32), 256, 0, stream>>>(qb, kb, vtg, cb, pos);
    transpose2048<<<tg, tb, 0, stream>>>(wo, wt);
    gemm_bt<<<dim3(32, 16, 1), 256, 0, stream>>>(cb, wt, d_out, 0, 0, 0);
  }
}

// Round 13
// 403.785 us; speedup vs baseline: 1.0461x; 1.0420x over previous
//
#include <hip/hip_runtime.h>
#include <hip/hip_bf16.h>
#include <math.h>

#define NH 16
#define DH 128
#define DM 2048
#define BB 2
#define TT 2048

typedef unsigned short u16;
typedef __attribute__((ext_vector_type(8))) __bf16 bf16x8;
typedef __attribute__((ext_vector_type(8))) u16 u16x8;
typedef __attribute__((ext_vector_type(4))) u16 u16x4;
typedef __attribute__((ext_vector_type(4))) float f32x4;

__device__ __forceinline__ float bf2f(u16 a){
  union { unsigned u; float f; } v; v.u = ((unsigned)a) << 16; return v.f;
}
__device__ __forceinline__ u16 f2bf(float f){
  union { float f; unsigned u; } v; v.f = f;
  unsigned r = v.u + 0x7fffu + ((v.u >> 16) & 1u);  // RNE
  return (u16)(r >> 16);
}
__device__ __forceinline__ __bf16 f2bfh(float f){
  u16 r = f2bf(f); __bf16 h; __builtin_memcpy(&h, &r, 2); return h;
}
__device__ __forceinline__ float bfh2f(__bf16 h){
  u16 r; __builtin_memcpy(&r, &h, 2); return bf2f(r);
}

// async global->LDS, 16B per lane. LDS dest = wave-uniform base + lane*16.
typedef const __attribute__((address_space(1))) unsigned int* gas_p;
typedef __attribute__((address_space(3))) unsigned int* las_p;
__device__ __forceinline__ void gl_lds16(const u16* g, u16* lds_uniform_base){
  __builtin_amdgcn_global_load_lds((gas_p)(const void*)g,
                                   (las_p)(void*)lds_uniform_base, 16, 0, 0);
}

#define SB() do{ asm volatile("" ::: "memory"); \
                 __builtin_amdgcn_s_barrier();  \
                 asm volatile("" ::: "memory"); }while(0)
#define WAITV8 asm volatile("s_waitcnt vmcnt(8)" ::: "memory")
#define WAITV0 asm volatile("s_waitcnt vmcnt(0)" ::: "memory")

// ---------------- prep4: 3 weight transposes (z<3) + x cvt (z==3) ----------
__global__ __launch_bounds__(256)
void prep4(const float* __restrict__ w0, const float* __restrict__ w1,
           const float* __restrict__ w2, const float* __restrict__ x,
           u16* __restrict__ dst, u16* __restrict__ xb){
  __shared__ u16 tile[32][33];
  const int z = blockIdx.z;
  const int tx = threadIdx.x, ty = threadIdx.y;
  if (z == 3){
    const int bid = blockIdx.y * 64 + blockIdx.x;
    const int tid = ty * 32 + tx;
    #pragma unroll
    for (int rep = 0; rep < 2; rep++){
      const int i = bid * 512 + rep * 256 + tid;
      const f32x4 v = *(const f32x4*)(x + (size_t)i * 4);
      u16x4 o;
      #pragma unroll
      for (int j = 0; j < 4; j++) o[j] = f2bf(v[j]);
      *(u16x4*)(xb + (size_t)i * 4) = o;
    }
    return;
  }
  const float* W = (z == 0) ? w0 : (z == 1) ? w1 : w2;
  u16* Wt = dst + (size_t)z * DM * DM;
  const int bx = blockIdx.x * 32, by = blockIdx.y * 32;
  #pragma unroll
  for (int i = 0; i < 32; i += 8)
    tile[ty + i][tx] = f2bf(W[(size_t)(by + ty + i) * DM + bx + tx]);
  __syncthreads();
  #pragma unroll
  for (int i = 0; i < 32; i += 8)
    Wt[(size_t)(bx + ty + i) * DM + by + tx] = tile[tx][ty + i];
}

// ---------------- W fp32 [K,N] -> Wt bf16 [N,K] (single, for wo) -----------
__global__ __launch_bounds__(256)
void transpose2048(const float* __restrict__ W, u16* __restrict__ Wt){
  __shared__ u16 tile[32][33];
  const int tx = threadIdx.x, ty = threadIdx.y;
  const int bx = blockIdx.x * 32, by = blockIdx.y * 32;
  #pragma unroll
  for (int i = 0; i < 32; i += 8)
    tile[ty + i][tx] = f2bf(W[(size_t)(by + ty + i) * DM + bx + tx]);
  __syncthreads();
  #pragma unroll
  for (int i = 0; i < 32; i += 8)
    Wt[(size_t)(bx + ty + i) * DM + by + tx] = tile[tx][ty + i];
}

// ---------------- fp32 -> bf16 elementwise (fallback path) ----------------
__global__ __launch_bounds__(256)
void cvt_f32_bf16(const float* __restrict__ src, u16* __restrict__ dst, int n4){
  const int i = blockIdx.x * 256 + threadIdx.x;
  if (i >= n4) return;
  const f32x4 v = *(const f32x4*)(src + (size_t)i * 4);
  u16x4 o;
  #pragma unroll
  for (int j = 0; j < 4; j++) o[j] = f2bf(v[j]);
  *(u16x4*)(dst + (size_t)i * 4) = o;
}

// ---------------- 128x128 GEMM, fused z (m97 structure; CLOSED family) -----
// R1/R2/R4/R10/R11: five structure variants (counted-vmcnt k-half, 3-buf,
// 256^2 8-phase, 128x256 8-wave +/- v7 sync) all 150-215us vs this at 145.
// R12: K-rope fused into the mode-3 epilogue (block's N-range = one head, so
// the rotation pair (dh, dh+64) is block-local). Stage C-tile into the dead
// As/Bs LDS in mode-3 swizzled layout, barrier, rope 32 pairs/thread, write
// kb coalesced. Replaces the separate ropek kernel (launch ~7.5us + ~8us).
// Epilogue destinations selected BY MODE (mode3->Ck, mode2->Cv, else C0) so
// both z-fused and single-slice launches are safe (R12 audit fix).
__global__ __launch_bounds__(256)
void gemm_bt(const u16* __restrict__ A, const u16* __restrict__ Bt_base,
             void* __restrict__ C0, u16* __restrict__ Ck, u16* __restrict__ Cv,
             int mode0, const int* __restrict__ posp){
  __shared__ u16 SMEM[16384];                       // 32KB: staging / C-tile
  u16 (*As)[128][32] = (u16 (*)[128][32])SMEM;      // [2][128][32]
  u16 (*Bs)[128][32] = (u16 (*)[128][32])(SMEM + 8192);
  const int z = blockIdx.z;
  const u16* Bt = Bt_base + (size_t)z * DM * DM;
  const int mode = (z == 0) ? mode0 : (z == 1) ? 3 : 2;

  const int tid = threadIdx.x;
  const int wave = tid >> 6, lane = tid & 63;
  const int wm = wave & 1, wn = wave >> 1;
  const int row16 = lane & 15, quad = lane >> 4;
  const int m0 = blockIdx.x * 128, n0 = blockIdx.y * 128;

  const f32x4 zero = {0.f, 0.f, 0.f, 0.f};
  f32x4 acc[4][4];
  #pragma unroll
  for (int i = 0; i < 4; i++)
    #pragma unroll
    for (int j = 0; j < 4; j++) acc[i][j] = zero;

  const int srow = lane >> 2;           // 0..15 within 16-row chunk
  const int scol = (lane & 3) * 8;      // u16 units, 16B per lane

  for (int k0 = 0; k0 < DM; k0 += 64){
    #pragma unroll
    for (int c = 0; c < 2; c++){
      const int rbase = wave * 32 + c * 16;
      const u16* pa = A  + (size_t)(m0 + rbase + srow) * DM + k0 + scol;
      const u16* pb = Bt + (size_t)(n0 + rbase + srow) * DM + k0 + scol;
      gl_lds16(pa,      &As[0][rbase][0]);
      gl_lds16(pa + 32, &As[1][rbase][0]);
      gl_lds16(pb,      &Bs[0][rbase][0]);
      gl_lds16(pb + 32, &Bs[1][rbase][0]);
    }
    __syncthreads();
    #pragma unroll
    for (int buf = 0; buf < 2; buf++){
      bf16x8 af[4], bfr[4];
      #pragma unroll
      for (int mt = 0; mt < 4; mt++)
        af[mt] = *(const bf16x8*)&As[buf][wm * 64 + mt * 16 + row16][quad * 8];
      #pragma unroll
      for (int nt = 0; nt < 4; nt++)
        bfr[nt] = *(const bf16x8*)&Bs[buf][wn * 64 + nt * 16 + row16][quad * 8];
      #pragma unroll
      for (int mt = 0; mt < 4; mt++)
        #pragma unroll
        for (int nt = 0; nt < 4; nt++)
          acc[mt][nt] = __builtin_amdgcn_mfma_f32_16x16x32_bf16(af[mt], bfr[nt], acc[mt][nt], 0, 0, 0);
    }
    __syncthreads();
  }

  if (mode == 3){
    // ---- fused K-rope epilogue ----
    // (1) store acc as bf16 into SMEM[ml][nl ^ ((ml&7)<<3)] — exactly the
    //     mode-3 swizzled tile layout (n0 covers one head => dh = nl;
    //     t&7 == ml&7 since m0 % 128 == 0; XOR never touches bit 6).
    #pragma unroll
    for (int mt = 0; mt < 4; mt++)
      #pragma unroll
      for (int nt = 0; nt < 4; nt++)
        #pragma unroll
        for (int r = 0; r < 4; r++){
          const int ml = wm * 64 + mt * 16 + quad * 4 + r;
          const int nl = wn * 64 + nt * 16 + row16;
          SMEM[ml * 128 + (nl ^ ((ml & 7) << 3))] = f2bf(acc[mt][nt][r]);
        }
    __syncthreads();
    // (2) rope pairs (physical ps, ps+64): logical dh_lo = ps ^ fx (< 64),
    //     partner dh_lo+64 lives at physical ps+64. 2 threads/row, 32
    //     pairs each, coalesced u16x8 global writes.
    int p0 = *posp; if (p0 < 0) p0 = 0;
    const int ml = tid >> 1;                 // 0..127
    const int half = tid & 1;
    const int mg = m0 + ml;
    const int tglob = mg & (TT - 1);
    const int b = mg >> 11, hh = n0 >> 7;
    const float tf = (float)(p0 + tglob);
    const int fx = (tglob & 7) << 3;
    u16* krow = Ck + (((size_t)(b * NH + hh) * TT + tglob) * DH);
    #pragma unroll
    for (int jj = 0; jj < 4; jj++){
      const int ps = half * 32 + jj * 8;
      u16x8 lo = *(const u16x8*)&SMEM[ml * 128 + ps];
      u16x8 hi = *(const u16x8*)&SMEM[ml * 128 + ps + 64];
      #pragma unroll
      for (int j = 0; j < 8; j++){
        const int pl = (ps + j) ^ fx;        // logical dh (< 64)
        const float inv = __expf(-(float)pl * (9.2103403719761836f / 64.f));
        const float a = tf * inv;
        const float sn = __sinf(a), cs = __cosf(a);
        const float k1 = bf2f(lo[j]), k2 = bf2f(hi[j]);
        lo[j] = f2bf(k1 * cs - k2 * sn);
        hi[j] = f2bf(k1 * sn + k2 * cs);
      }
      *(u16x8*)(krow + ps)      = lo;
      *(u16x8*)(krow + ps + 64) = hi;
    }
    return;
  }

  // epilogue (modes 0/1/2): C/D layout row = quad*4+reg, col = lane&15
  #pragma unroll
  for (int mt = 0; mt < 4; mt++){
    #pragma unroll
    for (int nt = 0; nt < 4; nt++){
      #pragma unroll
      for (int r = 0; r < 4; r++){
        const int m = m0 + wm * 64 + mt * 16 + quad * 4 + r;
        const int n = n0 + wn * 64 + nt * 16 + row16;
        const int b = m >> 11, t = m & (TT - 1);
        const int hh = n >> 7, dh = n & (DH - 1);
        if (mode == 1){
          ((u16*)C0)[(((size_t)(b * NH + hh) * TT + t) * DH) + dh] = f2bf(acc[mt][nt][r]);
        } else if (mode == 2){
          const int ts = (t & 63) ^ ((dh & 7) << 3);
          Cv[(((size_t)(b * NH + hh) * 32 + (t >> 6)) * 8192) + dh * 64 + ts] = f2bf(acc[mt][nt][r]);
        } else {
          ((float*)C0)[(size_t)m * DM + n] = acc[mt][nt][r];
        }
      }
    }
  }
}

// ---------------- causal flash attention v9 (R9/R11-proven) ----------------
template<bool MASK>
__device__ __forceinline__ void attn_tile(
    int kt0, int qbase, int wave, int row16, int quad,
    const bf16x8 (&qf)[4],
    u16 (&k_s)[64][128], u16 (&vt_s)[128][64], u16 (&p_s)[4][16][68],
    f32x4 (&o_acc)[8], float (&l_acc)[4])
{
  const float scale = 0.08838834764831845f;  // 1/sqrt(128)
  const f32x4 zero = {0.f, 0.f, 0.f, 0.f};
  const int fx = (row16 & 7) << 3;           // XOR de-swizzle
  f32x4 s_acc[4];
  #pragma unroll
  for (int nt = 0; nt < 4; nt++) s_acc[nt] = zero;
  __builtin_amdgcn_s_setprio(1);
  #pragma unroll
  for (int st = 0; st < 4; st++)
    #pragma unroll
    for (int nt = 0; nt < 4; nt++){
      const bf16x8 kf = *(const bf16x8*)&k_s[nt * 16 + row16][(st * 32 + quad * 8) ^ fx];
      s_acc[nt] = __builtin_amdgcn_mfma_f32_16x16x32_bf16(qf[st], kf, s_acc[nt], 0, 0, 0);
    }
  __builtin_amdgcn_s_setprio(0);
  #pragma unroll
  for (int r = 0; r < 4; r++){
    float ps = 0.f;
    #pragma unroll
    for (int nt = 0; nt < 4; nt++){
      float p = __expf(s_acc[nt][r] * scale);
      if (MASK){
        const int qr = qbase + quad * 4 + r;
        if (kt0 + nt * 16 + row16 > qr) p = 0.f;
      }
      ps += p;
      p_s[wave][quad * 4 + r][nt * 16 + row16] = f2bf(p);
    }
    l_acc[r] += ps;
  }
  asm volatile("" ::: "memory");  // p_s wave-private; DS in-order per wave

  __builtin_amdgcn_s_setprio(1);
  #pragma unroll
  for (int kk = 0; kk < 2; kk++){
    const bf16x8 pf = *(const bf16x8*)&p_s[wave][row16][kk * 32 + quad * 8];
    #pragma unroll
    for (int nd = 0; nd < 8; nd++){
      const bf16x8 vb = *(const bf16x8*)&vt_s[nd * 16 + row16][(kk * 32 + quad * 8) ^ fx];
      o_acc[nd] = __builtin_amdgcn_mfma_f32_16x16x32_bf16(pf, vb, o_acc[nd], 0, 0, 0);
    }
  }
  __builtin_amdgcn_s_setprio(0);
}

__device__ __forceinline__ void owrite(
    u16* __restrict__ ctx, int bh, int qbase, int row16, int quad,
    f32x4 (&o_acc)[8], float (&l_acc)[4])
{
  #pragma unroll
  for (int r = 0; r < 4; r++){
    #pragma unroll
    for (int off = 1; off < 16; off <<= 1) l_acc[r] += __shfl_xor(l_acc[r], off, 64);
  }
  const int b = bh >> 4, h = bh & 15;
  #pragma unroll
  for (int nd = 0; nd < 8; nd++){
    #pragma unroll
    for (int r = 0; r < 4; r++){
      const int qr = qbase + quad * 4 + r;
      const size_t off = ((size_t)b * TT + qr) * DM + h * DH + nd * 16 + row16;
      ctx[off] = f2bf(o_acc[nd][r] / l_acc[r]);
    }
  }
}

__global__ __launch_bounds__(256)
void attn_fwd(const u16* __restrict__ q, const u16* __restrict__ k,
              const u16* __restrict__ vtg, u16* __restrict__ ctx,
              const int* __restrict__ posp){
  __shared__ u16 k_s[2][64][128];   // 32KB double-buffered [key][dh']
  __shared__ u16 vt_s[2][128][64];  // 32KB double-buffered [dh][t']
  __shared__ u16 p_s[4][16][68];    // 8.7KB per-wave P [q][key]
  const int tid = threadIdx.x;
  const int wave = tid >> 6, lane = tid & 63;
  const int row16 = lane & 15, quad = lane >> 4;
  const int i = blockIdx.x;         // 0..15
  const int bh = blockIdx.y;        // 0..31
  int p0 = *posp; if (p0 < 0) p0 = 0;
  const size_t bho = (size_t)bh * TT * DH;

  const int qbH = (31 - i) * 64 + wave * 16;   // heavy q-tile
  const int qbL = i * 64 + wave * 16;          // light q-tile (tiles subset)
  const int nT = 32 - i;                        // staged tiles t = 0..nT-1

  // fused Q-RoPE for both q-tiles, sharing the 16 inv-freq exps
  bf16x8 qfH[4], qfL[4];
  {
    const u16* qpH = q + bho + (size_t)(qbH + row16) * DH + quad * 8;
    const u16* qpL = q + bho + (size_t)(qbL + row16) * DH + quad * 8;
    #pragma unroll
    for (int st = 0; st < 4; st++){
      qfH[st] = *(const bf16x8*)(qpH + st * 32);
      qfL[st] = *(const bf16x8*)(qpL + st * 32);
    }
    const float tfH = (float)(p0 + qbH + row16);
    const float tfL = (float)(p0 + qbL + row16);
    #pragma unroll
    for (int st = 0; st < 2; st++){
      #pragma unroll
      for (int j = 0; j < 8; j++){
        const int dh = st * 32 + quad * 8 + j;
        const float inv = __expf(-(float)dh * (9.2103403719761836f / 64.f));
        float a = tfH * inv;
        float sn = __sinf(a), cs = __cosf(a);
        float lo = bfh2f(qfH[st][j]), hi = bfh2f(qfH[st + 2][j]);
        qfH[st][j]     = f2bfh(lo * cs - hi * sn);
        qfH[st + 2][j] = f2bfh(lo * sn + hi * cs);
        a = tfL * inv;
        sn = __sinf(a); cs = __cosf(a);
        lo = bfh2f(qfL[st][j]); hi = bfh2f(qfL[st + 2][j]);
        qfL[st][j]     = f2bfh(lo * cs - hi * sn);
        qfL[st + 2][j] = f2bfh(lo * sn + hi * cs);
      }
    }
  }

  float lH[4] = {0.f, 0.f, 0.f, 0.f}, lL[4] = {0.f, 0.f, 0.f, 0.f};
  const f32x4 zero = {0.f, 0.f, 0.f, 0.f};
  f32x4 oH[8], oL[8];
  #pragma unroll
  for (int j = 0; j < 8; j++){ oH[j] = zero; oL[j] = zero; }

  // DMA lane maps: K 1KB = 4 rows x 256B; V 1KB = 8 rows x 128B
  const int kl_r = lane >> 4, kl_c = (lane & 15) * 8;
  const int vl_r = lane >> 3, vl_c = (lane & 7) * 8;

  #define ASTAGE(t, db) do{ \
    const int kt = (t) * 64; \
    _Pragma("unroll") \
    for (int u = 0; u < 4; u++){ \
      const int rb = wave * 16 + u * 4; \
      gl_lds16(k + bho + (size_t)(kt + rb + kl_r) * DH + kl_c, &k_s[db][rb][0]); \
    } \
    const u16* vpan = vtg + ((size_t)bh * 32 + (t)) * 8192; \
    _Pragma("unroll") \
    for (int u = 0; u < 4; u++){ \
      const int rb = wave * 32 + u * 8; \
      gl_lds16(vpan + (size_t)(rb + vl_r) * 64 + vl_c, &vt_s[db][rb][0]); \
    } \
  }while(0)

  ASTAGE(0, 0);
  for (int t = 0; t < nT; ++t){
    const int db = t & 1;
    if (t + 1 < nT){
      ASTAGE(t + 1, db ^ 1);   // issue-early: covered by compute(t)
      WAITV8;                  // tile t landed; t+1 stays in flight
    } else {
      WAITV0;                  // last tile: drain
    }
    SB();                      // all waves' tile-t DMAs visible
    // heavy q: every tile; diagonal (mask) at t == nT-1
    if (t < nT - 1)
      attn_tile<false>(t * 64, qbH, wave, row16, quad, qfH, k_s[db], vt_s[db], p_s, oH, lH);
    else
      attn_tile<true >(t * 64, qbH, wave, row16, quad, qfH, k_s[db], vt_s[db], p_s, oH, lH);
    // light q: tiles t <= i only; diagonal at t == i
    if (t < i)
      attn_tile<false>(t * 64, qbL, wave, row16, quad, qfL, k_s[db], vt_s[db], p_s, oL, lL);
    else if (t == i)
      attn_tile<true >(t * 64, qbL, wave, row16, quad, qfL, k_s[db], vt_s[db], p_s, oL, lL);
    SB();                      // buf t free for restage (reads consumed)
  }
  #undef ASTAGE

  owrite(ctx, bh, qbH, row16, quad, oH, lH);
  owrite(ctx, bh, qbL, row16, quad, oL, lL);
}

extern "C" void kernel_launch(void* const* d_in, const int* in_sizes, int n_in,
                              void* d_out, int out_size, void* d_ws, size_t ws_size,
                              hipStream_t stream){
  const float* x  = (const float*)d_in[0];   // fp32 per reference
  const float* wq = (const float*)d_in[1];
  const float* wk = (const float*)d_in[2];
  const float* wv = (const float*)d_in[3];
  const float* wo = (const float*)d_in[4];
  const int* pos  = (const int*)d_in[5];

  char* ws = (char*)d_ws;
  const dim3 tg(64, 64), tb(32, 8);

  if (ws_size >= 92274688ull){
    // fused path: xb 16MB | wt3 25.2MB | qb 16 | kb 16 | vtg 16 = 92.3MB
    u16* xb  = (u16*)ws;                  u16* cb = xb;
    u16* wt3 = (u16*)(ws + 16777216);
    u16* qb  = (u16*)(ws + 41943040);
    u16* kb  = (u16*)(ws + 58720256);
    u16* vtg = (u16*)(ws + 75497472);

    prep4<<<dim3(64, 64, 4), tb, 0, stream>>>(wq, wk, wv, x, wt3, xb);
    gemm_bt<<<dim3(32, 16, 3), 256, 0, stream>>>(xb, wt3, qb, kb, vtg, 1, pos);
    transpose2048<<<tg, tb, 0, stream>>>(wo, wt3);   // slot0 (wq^T) dead; hoisted
    attn_fwd<<<dim3(16, 32), 256, 0, stream>>>(qb, kb, vtg, cb, pos);
    gemm_bt<<<dim3(32, 16, 1), 256, 0, stream>>>(cb, wt3, d_out, 0, 0, 0, pos);
  } else {
    // fallback (75.5MB): xb/cb 16 | wt 8 | qb 16 | kb 16 | vtg 16
    u16* xb  = (u16*)ws;                  u16* cb = xb;
    u16* wt  = (u16*)(ws + 16777216);
    u16* qb  = (u16*)(ws + 25165824);
    u16* kb  = (u16*)(ws + 41943040);
    u16* vtg = (u16*)(ws + 58720256);

    cvt_f32_bf16<<<8192, 256, 0, stream>>>(x, xb, 2097152);
    transpose2048<<<tg, tb, 0, stream>>>(wq, wt);
    gemm_bt<<<dim3(32, 16, 1), 256, 0, stream>>>(xb, wt, qb, 0, 0, 1, pos);
    transpose2048<<<tg, tb, 0, stream>>>(wk, wt);
    gemm_bt<<<dim3(32, 16, 1), 256, 0, stream>>>(xb, wt, 0, kb, 0, 3, pos);
    transpose2048<<<tg, tb, 0, stream>>>(wv, wt);
    gemm_bt<<<dim3(32, 16, 1), 256, 0, stream>>>(xb, wt, 0, 0, vtg, 2, pos);
    attn_fwd<<<dim3(16, 32), 256, 0, stream>>>(qb, kb, vtg, cb, pos);
    transpose2048<<<tg, tb, 0, stream>>>(wo, wt);
    gemm_bt<<<dim3(32, 16, 1), 256, 0, stream>>>(cb, wt, d_out, 0, 0, 0, pos);
  }
}